// Round 1
// baseline (122.014 us; speedup 1.0000x reference)
//
#include <hip/hip_runtime.h>

// Per-feature 1->10->1 MLP, fused.
//   out[r, d] = sum_j relu(x[r,d]*W1[d,j] + b1[d,j]) * W2[d,j] + b2[d]
//
// Strategy: each thread owns 4 consecutive features (one float4 lane of a row)
// and keeps all 124 per-feature params in registers (loaded once via
// contiguous float4 loads — W1[d0*10 .. d0*10+40) is contiguous). It then
// streams over its assigned rows with fully-coalesced float4 load/compute/store.
// Consecutive lanes -> consecutive feature groups -> 1 KiB contiguous per wave.

constexpr int D = 768;
constexpr int H = 10;
constexpr int GROUPS = D / 4;  // 192 float4 groups per row

__global__ __launch_bounds__(256, 3)
void mlp_fused(const float* __restrict__ x,
               const float* __restrict__ W1,
               const float* __restrict__ b1,
               const float* __restrict__ W2,
               const float* __restrict__ b2,
               float* __restrict__ out,
               int totalRows, int rowSlots) {
    const int tid   = blockIdx.x * blockDim.x + threadIdx.x;
    const int g     = tid % GROUPS;   // feature group (4 features)
    const int rslot = tid / GROUPS;   // starting row
    const int d0    = g * 4;

    // ---- Load per-feature params into registers (once per thread) ----
    // Each array is 40 contiguous floats = 10 float4 loads, 16B-aligned.
    float p1[40], q1[40], p2[40];
    const float4* W1v = reinterpret_cast<const float4*>(W1 + d0 * H);
    const float4* b1v = reinterpret_cast<const float4*>(b1 + d0 * H);
    const float4* W2v = reinterpret_cast<const float4*>(W2 + d0 * H);
#pragma unroll
    for (int i = 0; i < 10; ++i) {
        float4 v = W1v[i];
        p1[4*i+0] = v.x; p1[4*i+1] = v.y; p1[4*i+2] = v.z; p1[4*i+3] = v.w;
        float4 u = b1v[i];
        q1[4*i+0] = u.x; q1[4*i+1] = u.y; q1[4*i+2] = u.z; q1[4*i+3] = u.w;
        float4 w = W2v[i];
        p2[4*i+0] = w.x; p2[4*i+1] = w.y; p2[4*i+2] = w.z; p2[4*i+3] = w.w;
    }
    const float4 bb2 = *reinterpret_cast<const float4*>(b2 + d0);

    const float4* xv = reinterpret_cast<const float4*>(x);
    float4*       ov = reinterpret_cast<float4*>(out);

    // ---- Stream rows: coalesced float4 in / float4 out ----
#pragma unroll 4
    for (int r = rslot; r < totalRows; r += rowSlots) {
        const int idx = r * GROUPS + g;
        float4 xe = xv[idx];
        float e[4] = {xe.x, xe.y, xe.z, xe.w};
        float res[4];
#pragma unroll
        for (int f = 0; f < 4; ++f) {
            float acc = 0.0f;
#pragma unroll
            for (int j = 0; j < H; ++j) {
                float h = fmaf(e[f], p1[f*10 + j], q1[f*10 + j]);
                h = fmaxf(h, 0.0f);
                acc = fmaf(h, p2[f*10 + j], acc);
            }
            res[f] = acc;
        }
        float4 o;
        o.x = res[0] + bb2.x;
        o.y = res[1] + bb2.y;
        o.z = res[2] + bb2.z;
        o.w = res[3] + bb2.w;
        ov[idx] = o;
    }
}

extern "C" void kernel_launch(void* const* d_in, const int* in_sizes, int n_in,
                              void* d_out, int out_size, void* d_ws, size_t ws_size,
                              hipStream_t stream) {
    const float* x  = (const float*)d_in[0];
    const float* W1 = (const float*)d_in[1];
    const float* b1 = (const float*)d_in[2];
    const float* W2 = (const float*)d_in[3];
    const float* b2 = (const float*)d_in[4];
    float* out = (float*)d_out;

    const int totalRows = in_sizes[0] / D;           // 8192
    const int numBlocks = 768;                       // 3 blocks/CU on 256 CUs, no tail
    const int rowSlots  = numBlocks * 256 / GROUPS;  // 1024 row slots -> 8 rows/thread

    mlp_fused<<<numBlocks, 256, 0, stream>>>(x, W1, b1, W2, b2, out,
                                             totalRows, rowSlots);
}

// Round 2
// 96.416 us; speedup vs baseline: 1.2655x; 1.2655x over previous
//
#include <hip/hip_runtime.h>

// Per-feature 1->10->1 MLP, fused.
//   out[r, d] = sum_j relu(x[r,d]*W1[d,j] + b1[d,j]) * W2[d,j] + b2[d]
//
// R1 change vs R0: R0 gave each thread 4 features -> 124 param floats -> the
// compiler SPILLED the param arrays (VGPR=84, +30MB scratch writes, VALUBusy 8%).
// Now each thread owns 2 consecutive features: 62 param floats + working set
// fits comfortably in registers under __launch_bounds__(256,4) (cap 128 VGPR).
// Streaming access is float2 (8B/lane, fully coalesced); param loads are
// contiguous float4s done once per thread.

constexpr int D = 768;
constexpr int H = 10;
constexpr int GROUPS = D / 2;  // 384 float2 groups per row

__global__ __launch_bounds__(256, 4)
void mlp_fused(const float* __restrict__ x,
               const float* __restrict__ W1,
               const float* __restrict__ b1,
               const float* __restrict__ W2,
               const float* __restrict__ b2,
               float* __restrict__ out,
               int totalRows, int rowSlots) {
    const int tid   = blockIdx.x * blockDim.x + threadIdx.x;
    const int g     = tid % GROUPS;   // feature pair index
    const int rslot = tid / GROUPS;   // starting row slot
    const int d0    = g * 2;

    // ---- Per-thread params: 2 features x {W1,b1,W2}[10] = 60 floats + 2 bias.
    // W1[d0*10 .. d0*10+20) is contiguous; d0 even -> byte offset 80*g, 16B-aligned.
    float p1[20], q1[20], p2[20];
    const float4* W1v = reinterpret_cast<const float4*>(W1 + d0 * H);
    const float4* b1v = reinterpret_cast<const float4*>(b1 + d0 * H);
    const float4* W2v = reinterpret_cast<const float4*>(W2 + d0 * H);
#pragma unroll
    for (int i = 0; i < 5; ++i) {
        float4 v = W1v[i];
        p1[4*i+0] = v.x; p1[4*i+1] = v.y; p1[4*i+2] = v.z; p1[4*i+3] = v.w;
        float4 u = b1v[i];
        q1[4*i+0] = u.x; q1[4*i+1] = u.y; q1[4*i+2] = u.z; q1[4*i+3] = u.w;
        float4 w = W2v[i];
        p2[4*i+0] = w.x; p2[4*i+1] = w.y; p2[4*i+2] = w.z; p2[4*i+3] = w.w;
    }
    const float2 bb2 = *reinterpret_cast<const float2*>(b2 + d0);

    const float2* xv = reinterpret_cast<const float2*>(x);
    float2*       ov = reinterpret_cast<float2*>(out);

    // ---- Stream rows: coalesced float2 in / float2 out ----
#pragma unroll 4
    for (int r = rslot; r < totalRows; r += rowSlots) {
        const int idx = r * GROUPS + g;
        float2 xe = xv[idx];
        float acc0 = 0.0f, acc1 = 0.0f;
#pragma unroll
        for (int j = 0; j < H; ++j) {
            float h0 = fmaf(xe.x, p1[j], q1[j]);
            h0 = fmaxf(h0, 0.0f);
            acc0 = fmaf(h0, p2[j], acc0);
            float h1 = fmaf(xe.y, p1[10 + j], q1[10 + j]);
            h1 = fmaxf(h1, 0.0f);
            acc1 = fmaf(h1, p2[10 + j], acc1);
        }
        float2 o;
        o.x = acc0 + bb2.x;
        o.y = acc1 + bb2.y;
        ov[idx] = o;
    }
}

extern "C" void kernel_launch(void* const* d_in, const int* in_sizes, int n_in,
                              void* d_out, int out_size, void* d_ws, size_t ws_size,
                              hipStream_t stream) {
    const float* x  = (const float*)d_in[0];
    const float* W1 = (const float*)d_in[1];
    const float* b1 = (const float*)d_in[2];
    const float* W2 = (const float*)d_in[3];
    const float* b2 = (const float*)d_in[4];
    float* out = (float*)d_out;

    const int totalRows = in_sizes[0] / D;             // 8192
    const int numBlocks = 768;                         // 3 blocks/CU, no tail
    const int rowSlots  = numBlocks * 256 / GROUPS;    // 512 row slots -> 16 rows/thread

    mlp_fused<<<numBlocks, 256, 0, stream>>>(x, W1, b1, W2, b2, out,
                                             totalRows, rowSlots);
}

// Round 4
// 88.406 us; speedup vs baseline: 1.3802x; 1.0906x over previous
//
#include <hip/hip_runtime.h>

// Per-feature 1->10->1 MLP, fused.
//   out[r, d] = sum_j relu(x[r,d]*W1[d,j] + b1[d,j]) * W2[d,j] + b2[d]
//
// R3 = R2 with the compile fix: __builtin_nontemporal_store needs a native
// clang vector type, not HIP_vector_type<float,2>. Use ext_vector_type(2).
//
// R2 design (unchanged): explicit 4-deep software pipeline (cur[4]/nxt[4],
// 4-8 outstanding 512B loads/wave), 1536 blocks (4 blocks/CU), params for 2
// features/thread pinned in registers under __launch_bounds__(256,4).

constexpr int D = 768;
constexpr int H = 10;
constexpr int GROUPS = D / 2;  // 384 float2 groups per row

typedef float v2f __attribute__((ext_vector_type(2)));

__global__ __launch_bounds__(256, 4)
void mlp_fused(const float* __restrict__ x,
               const float* __restrict__ W1,
               const float* __restrict__ b1,
               const float* __restrict__ W2,
               const float* __restrict__ b2,
               float* __restrict__ out,
               int totalRows, int rowSlots) {
    const int tid   = blockIdx.x * blockDim.x + threadIdx.x;
    const int g     = tid % GROUPS;   // feature pair index
    const int rslot = tid / GROUPS;   // starting row slot
    const int d0    = g * 2;

    // ---- Per-thread params: 2 features x {W1,b1,W2}[10] = 60 floats + bias2.
    // W1[d0*10 .. d0*10+20) contiguous; d0 even -> offset 80*g bytes, 16B-aligned.
    float p1[20], q1[20], p2[20];
    const float4* W1v = reinterpret_cast<const float4*>(W1 + d0 * H);
    const float4* b1v = reinterpret_cast<const float4*>(b1 + d0 * H);
    const float4* W2v = reinterpret_cast<const float4*>(W2 + d0 * H);
#pragma unroll
    for (int i = 0; i < 5; ++i) {
        float4 v = W1v[i];
        p1[4*i+0] = v.x; p1[4*i+1] = v.y; p1[4*i+2] = v.z; p1[4*i+3] = v.w;
        float4 u = b1v[i];
        q1[4*i+0] = u.x; q1[4*i+1] = u.y; q1[4*i+2] = u.z; q1[4*i+3] = u.w;
        float4 w = W2v[i];
        p2[4*i+0] = w.x; p2[4*i+1] = w.y; p2[4*i+2] = w.z; p2[4*i+3] = w.w;
    }
    const float2 bb2 = *reinterpret_cast<const float2*>(b2 + d0);

    const v2f* xv = reinterpret_cast<const v2f*>(x);
    v2f*       ov = reinterpret_cast<v2f*>(out);

    const int stride = rowSlots;

    // ---- Software-pipelined stream: batches of 4 rows, prefetch next batch.
    int r = rslot;
    v2f cur[4];
#pragma unroll
    for (int k = 0; k < 4; ++k)
        cur[k] = xv[(size_t)(r + k * stride) * GROUPS + g];

    while (true) {
        const int rn = r + 4 * stride;
        const bool more = rn < totalRows;
        v2f nxt[4];
        if (more) {
#pragma unroll
            for (int k = 0; k < 4; ++k)
                nxt[k] = xv[(size_t)(rn + k * stride) * GROUPS + g];
        }
#pragma unroll
        for (int k = 0; k < 4; ++k) {
            const v2f xe = cur[k];
            float acc0 = 0.0f, acc1 = 0.0f;
#pragma unroll
            for (int j = 0; j < H; ++j) {
                float h0 = fmaf(xe.x, p1[j], q1[j]);
                h0 = fmaxf(h0, 0.0f);
                acc0 = fmaf(h0, p2[j], acc0);
                float h1 = fmaf(xe.y, p1[10 + j], q1[10 + j]);
                h1 = fmaxf(h1, 0.0f);
                acc1 = fmaf(h1, p2[10 + j], acc1);
            }
            v2f o;
            o.x = acc0 + bb2.x;
            o.y = acc1 + bb2.y;
            __builtin_nontemporal_store(o, &ov[(size_t)(r + k * stride) * GROUPS + g]);
        }
        if (!more) break;
        r = rn;
#pragma unroll
        for (int k = 0; k < 4; ++k) cur[k] = nxt[k];
    }
}

extern "C" void kernel_launch(void* const* d_in, const int* in_sizes, int n_in,
                              void* d_out, int out_size, void* d_ws, size_t ws_size,
                              hipStream_t stream) {
    const float* x  = (const float*)d_in[0];
    const float* W1 = (const float*)d_in[1];
    const float* b1 = (const float*)d_in[2];
    const float* W2 = (const float*)d_in[3];
    const float* b2 = (const float*)d_in[4];
    float* out = (float*)d_out;

    const int totalRows = in_sizes[0] / D;             // 8192
    const int numBlocks = 1536;                        // up to 4 blocks/CU resident
    const int rowSlots  = numBlocks * 256 / GROUPS;    // 1024 slots -> 8 rows/thread

    mlp_fused<<<numBlocks, 256, 0, stream>>>(x, W1, b1, W2, b2, out,
                                             totalRows, rowSlots);
}